// Round 10
// baseline (98.640 us; speedup 1.0000x reference)
//
#include <hip/hip_runtime.h>
#include <stdint.h>

typedef float  f32x4 __attribute__((ext_vector_type(4)));
typedef short  s16x8 __attribute__((ext_vector_type(8)));
typedef unsigned short u16;

#define KK 32768   /* NN*DD */

__device__ __forceinline__ u16 f2bf_rn(float f) {
  uint32_t u = __float_as_uint(f);
  u += 0x7fffu + ((u >> 16) & 1u);
  return (u16)(u >> 16);
}
__device__ __forceinline__ float bf2f(u16 h) {
  return __uint_as_float(((uint32_t)h) << 16);
}

// ---------------------------------------------------------------------------
// Kernel A: g_t[b][c][k] = x[b,s,c] * W[d,c], k = s*32+d, LINEAR layout,
// bf16 hi/lo planes. (GEMM reads fragments straight to registers.)
// ---------------------------------------------------------------------------
__global__ void build_g(const float* __restrict__ x, const float* __restrict__ W,
                        u16* __restrict__ ghi, u16* __restrict__ glo) {
  int t  = blockIdx.x * 256 + threadIdx.x;
  int k0 = (t & 4095) << 3;
  int c  = (t >> 12) & 63;
  int b  = t >> 18;
  int s  = k0 >> 5;
  int d0 = k0 & 31;
  float xv = x[(((b << 10) + s) << 6) + c];
  s16x8 vh, vl;
#pragma unroll
  for (int i = 0; i < 8; ++i) {
    float g = xv * W[((d0 + i) << 6) + c];
    u16 h = f2bf_rn(g);
    vh[i] = (short)h;
    vl[i] = (short)f2bf_rn(g - bf2f(h));
  }
  size_t off = (((size_t)((b << 6) + c)) << 15) + (size_t)k0;
  *reinterpret_cast<s16x8*>(ghi + off) = vh;
  *reinterpret_cast<s16x8*>(glo + off) = vl;
}

// ---------------------------------------------------------------------------
// Kernel B: DRAM-chunk-optimized streaming GEMM.
// Grid (1,128,2) = 256 WGs (1/CU), 512 thr = 8 waves (2 rf x 4 cf).
// WG owns k-window [ks*256,+256). B frags held in 64 VGPRs (loaded once).
// Per m-subtile (32 rows): threads reg-load 64B contiguous per row chunk
// (1KB/row), convert fp32->bf16 hi/lo once, ds_write swizzled; MFMA reads
// A frags from LDS (2-way-free banks), 24 MFMAs/wave. Triple-buffered A,
// depth-2 reg pipeline, 1 barrier/iter, counted vmcnt.
// LDS 96KB: buf q at q*32KB: [plane(2) x 16KB][row(32) x 512B] (k-XOR-swz).
// ---------------------------------------------------------------------------
#define MFMA16(A_, B_, C_) __builtin_amdgcn_mfma_f32_16x16x32_bf16((A_), (B_), (C_), 0, 0, 0)

__global__ __launch_bounds__(512) void gemm_stream(
    const float* __restrict__ kb, const u16* __restrict__ ghi,
    const u16* __restrict__ glo, float* __restrict__ part) {
  __shared__ unsigned char lds[98304];

  const int tid = threadIdx.x;
  const int w   = tid >> 6;
  const int l   = tid & 63;
  const int lr  = l & 15;
  const int lk  = l >> 4;
  const int ks  = blockIdx.y;
  const int b   = blockIdx.z;
  const int rf  = w >> 2;        // row-frag 0..1 (16 rows each)
  const int cf  = w & 3;         // col-frag 0..3

  // ---- B fragments -> registers, once (g planes are L3-resident) ----
  s16x8 BH[8], BL[8];
  {
    const size_t bo = (((size_t)((b << 6) + (cf << 4) + lr)) << 15)
                    + (size_t)(ks << 8) + (size_t)(lk << 3);
    const u16* ph = ghi + bo;
    const u16* pq = glo + bo;
#pragma unroll
    for (int kf = 0; kf < 8; ++kf) {
      BH[kf] = *reinterpret_cast<const s16x8*>(ph + kf * 32);
      BL[kf] = *reinterpret_cast<const s16x8*>(pq + kf * 32);
    }
  }

  // ---- A addressing ----
  const int rl   = tid >> 4;             // conversion row 0..31
  const int kc16 = (tid & 15) << 4;      // first of this thread's 16 k-elems
  const float* apg = kb + (((size_t)((b << 10) + rl)) << 15)
                        + (size_t)(ks << 8) + (size_t)kc16;   // + mt<<20
  const int wb   = rl * 512;             // conv-write row base (plane-rel)
  const int wswz = (rl & 7) << 4;
  const int arow = (rf << 4) + lr;       // frag-read row
  const int arb  = arow * 512;
  const int aswz = (arow & 7) << 4;

  float* const pbase = part + (((size_t)((b << 7) + ks)) << 16);

  f32x4 ra[4], rb[4];

#define LOADA(R_, mt_) do {                                                  \
    const float* p_ = apg + ((size_t)(mt_) << 20);                           \
    R_[0] = *reinterpret_cast<const f32x4*>(p_);                             \
    R_[1] = *reinterpret_cast<const f32x4*>(p_ + 4);                         \
    R_[2] = *reinterpret_cast<const f32x4*>(p_ + 8);                         \
    R_[3] = *reinterpret_cast<const f32x4*>(p_ + 12);                        \
  } while (0)

#define CONV(R_, buf_) do {                                                  \
    unsigned char* base_ = lds + (buf_) * 32768;                             \
    s16x8 h_[2], o_[2];                                                      \
    _Pragma("unroll")                                                        \
    for (int j = 0; j < 16; ++j) {                                           \
      float f_ = R_[j >> 2][j & 3];                                          \
      uint32_t u_ = __float_as_uint(f_);                                     \
      ((short*)h_)[j] = (short)(u16)(u_ >> 16);                              \
      ((short*)o_)[j] = (short)f2bf_rn(f_ - __uint_as_float(u_ & 0xffff0000u)); \
    }                                                                        \
    *reinterpret_cast<s16x8*>(base_ + wb + (((kc16 << 1)     ) ^ wswz)) = h_[0]; \
    *reinterpret_cast<s16x8*>(base_ + wb + (((kc16 << 1) + 16) ^ wswz)) = h_[1]; \
    *reinterpret_cast<s16x8*>(base_ + 16384 + wb + (((kc16 << 1)     ) ^ wswz)) = o_[0]; \
    *reinterpret_cast<s16x8*>(base_ + 16384 + wb + (((kc16 << 1) + 16) ^ wswz)) = o_[1]; \
  } while (0)

#define MFMAPH(mt_) do {                                                     \
    const unsigned char* base_ = lds + ((mt_) % 3) * 32768;                  \
    f32x4 acc_ = {0.f, 0.f, 0.f, 0.f};                                       \
    _Pragma("unroll")                                                        \
    for (int kf = 0; kf < 8; ++kf) {                                         \
      int kb_ = (kf << 6) + (lk << 4);                                       \
      s16x8 ah_ = *reinterpret_cast<const s16x8*>(base_ + arb + (kb_ ^ aswz)); \
      s16x8 al_ = *reinterpret_cast<const s16x8*>(base_ + 16384 + arb + (kb_ ^ aswz)); \
      acc_ = MFMA16(ah_, BH[kf], acc_);                                      \
      acc_ = MFMA16(al_, BH[kf], acc_);                                      \
      acc_ = MFMA16(ah_, BL[kf], acc_);                                      \
    }                                                                        \
    _Pragma("unroll")                                                        \
    for (int i = 0; i < 4; ++i) {                                            \
      int rr_ = ((mt_) << 5) + (rf << 4) + (lk << 2) + i;                    \
      pbase[((size_t)rr_ << 6) + (cf << 4) + lr] = acc_[i];                  \
    }                                                                        \
  } while (0)

  // ---- prologue: fill bufs 0,1; loads for 2,3 in flight ----
  LOADA(ra, 0);
  LOADA(rb, 1);
  asm volatile("s_waitcnt vmcnt(4)" ::: "memory");   // B(16)+ra(4) done
  CONV(ra, 0);
  LOADA(ra, 2);
  asm volatile("s_waitcnt vmcnt(4)" ::: "memory");   // rb(1) done
  CONV(rb, 1);
  LOADA(rb, 3);
  asm volatile("s_waitcnt lgkmcnt(0)" ::: "memory");
  __builtin_amdgcn_sched_barrier(0);
  __builtin_amdgcn_s_barrier();

  // ---- main loop: 32 m-subtiles, unrolled x2 for static reg-set parity ----
  for (int mt = 0; mt < 32; mt += 2) {
    // even iter (reg set ra)
    MFMAPH(mt);
    asm volatile("s_waitcnt vmcnt(8)" ::: "memory"); // loads(mt+2) landed
    __builtin_amdgcn_sched_barrier(0);
    if (mt + 2 < 32) CONV(ra, (mt + 2) % 3);
    if (mt + 4 < 32) LOADA(ra, mt + 4);
    asm volatile("s_waitcnt lgkmcnt(0)" ::: "memory");
    __builtin_amdgcn_sched_barrier(0);
    __builtin_amdgcn_s_barrier();
    // odd iter (reg set rb)
    MFMAPH(mt + 1);
    asm volatile("s_waitcnt vmcnt(8)" ::: "memory"); // loads(mt+3) landed
    __builtin_amdgcn_sched_barrier(0);
    if (mt + 3 < 32) CONV(rb, (mt + 3) % 3);
    if (mt + 5 < 32) LOADA(rb, mt + 5);
    asm volatile("s_waitcnt lgkmcnt(0)" ::: "memory");
    __builtin_amdgcn_sched_barrier(0);
    __builtin_amdgcn_s_barrier();
  }
#undef LOADA
#undef CONV
#undef MFMAPH
}

// ---------------------------------------------------------------------------
// Kernel C: per (b,r): reduce Sk partials + conv_bias -> LayerNorm -> MLP.
// ---------------------------------------------------------------------------
__device__ __forceinline__ float gelu_tanh(float v) {
  float u = 0.7978845608028654f * (v + 0.044715f * v * v * v);
  float e = __expf(2.0f * u);
  float th = 1.0f - 2.0f / (e + 1.0f);
  return 0.5f * v * (1.0f + th);
}

__global__ __launch_bounds__(256) void epilogue(
    const float* __restrict__ part, const float* __restrict__ conv_bias,
    const float* __restrict__ ln_scale, const float* __restrict__ ln_bias,
    const float* __restrict__ W1, const float* __restrict__ b1,
    const float* __restrict__ W2, const float* __restrict__ b2,
    float* __restrict__ out, int Sk) {
  __shared__ float red[4][64];
  __shared__ float nbuf[64];
  __shared__ float hbuf[256];

  const int tid = threadIdx.x;
  const int b = blockIdx.x >> 10;
  const int r = blockIdx.x & 1023;
  const int c = tid & 63;
  const int q = tid >> 6;

  float s = 0.0f;
  for (int ks = q; ks < Sk; ks += 4)
    s += part[(((size_t)(b * Sk + ks)) << 16) + ((size_t)r << 6) + c];
  red[q][c] = s;
  __syncthreads();

  if (q == 0) {
    float a = red[0][c] + red[1][c] + red[2][c] + red[3][c] + conv_bias[c];
    float sum = a;
#pragma unroll
    for (int off = 32; off >= 1; off >>= 1) sum += __shfl_xor(sum, off);
    float mu = sum * (1.0f / 64.0f);
    float d = a - mu;
    float ss = d * d;
#pragma unroll
    for (int off = 32; off >= 1; off >>= 1) ss += __shfl_xor(ss, off);
    float var = ss * (1.0f / 64.0f);
    nbuf[c] = d * rsqrtf(var + 1e-6f) * ln_scale[c] + ln_bias[c];
  }
  __syncthreads();

  {
    float acc = b1[tid];
#pragma unroll 8
    for (int cc = 0; cc < 64; ++cc) acc += nbuf[cc] * W1[(cc << 8) + tid];
    hbuf[tid] = gelu_tanh(acc);
  }
  __syncthreads();

  {
    float po = 0.0f;
#pragma unroll 8
    for (int jj = 0; jj < 64; ++jj) {
      int j = (q << 6) + jj;
      po += hbuf[j] * W2[(j << 6) + c];
    }
    red[q][c] = po;
  }
  __syncthreads();
  if (tid < 64) {
    float o = red[0][c] + red[1][c] + red[2][c] + red[3][c] + b2[c];
    out[(((size_t)(b << 10) + r) << 6) + c] = o;
  }
}

// ---------------------------------------------------------------------------
extern "C" void kernel_launch(void* const* d_in, const int* in_sizes, int n_in,
                              void* d_out, int out_size, void* d_ws, size_t ws_size,
                              hipStream_t stream) {
  const float* x         = (const float*)d_in[0];
  const float* kb        = (const float*)d_in[1];
  const float* kernel_W  = (const float*)d_in[2];
  const float* conv_bias = (const float*)d_in[3];
  const float* ln_scale  = (const float*)d_in[4];
  const float* ln_bias   = (const float*)d_in[5];
  const float* W1        = (const float*)d_in[6];
  const float* b1        = (const float*)d_in[7];
  const float* W2        = (const float*)d_in[8];
  const float* b2        = (const float*)d_in[9];
  float* out = (float*)d_out;

  // Workspace: ghi 8.4MB | glo 8.4MB | part 128*2*256KB = 67MB (ws ~1GB)
  char* wsb = (char*)d_ws;
  u16* ghi = (u16*)wsb;
  u16* glo = (u16*)(wsb + 8388608);
  float* part = (float*)(wsb + 16777216);
  const int Sk = 128;   // one 256-k window per WG

  build_g<<<2048, 256, 0, stream>>>(x, kernel_W, ghi, glo);
  gemm_stream<<<dim3(1, Sk, 2), 512, 0, stream>>>(kb, ghi, glo, part);
  epilogue<<<dim3(2048), 256, 0, stream>>>(part, conv_bias, ln_scale, ln_bias,
                                           W1, b1, W2, b2, out, Sk);
}